// Round 1
// baseline (106.394 us; speedup 1.0000x reference)
//
#include <hip/hip_runtime.h>

#define R_    116
#define RP    128
#define DIN_  116
#define H_    256
#define BZ_   512

typedef float  f32x4  __attribute__((ext_vector_type(4)));
typedef short  short8 __attribute__((ext_vector_type(8)));
typedef short  short4v __attribute__((ext_vector_type(4)));
typedef int    int4v  __attribute__((ext_vector_type(4)));

// ---- LDS layout (bytes) ----
#define AT_OFF   0          // At [128][136] bf16 : At[c][r] = max(m[r][c],0) + (r==c)
#define AT_P     136
#define H1_OFF   34816      // H1 [128][264] bf16 : h1[c][f]
#define H1_P     264
#define XST_OFF  102400     // xsT [64][136] bf16 : xs[f_local][r]
#define XST_P    136
#define WB_OFF   119808     // Wbuf: layer1 [64][136], layer2 [64][264] bf16
#define DINV_OFF 153600     // 128 f32
#define RED_OFF  154112     // 16 f32
#define LDS_SIZE 154176

__device__ __forceinline__ short f2bf(float f) {
  union { float f; unsigned u; } x; x.f = f;
  unsigned r = x.u + 0x7fffu + ((x.u >> 16) & 1u);
  return (short)(r >> 16);
}
__device__ __forceinline__ float bf2f(short s) {
  union { unsigned u; float f; } x;
  x.u = ((unsigned)(unsigned short)s) << 16;
  return x.f;
}

// Pre-transpose weights to bf16 Wt[f][k] with zero-padded K.
__global__ void __launch_bounds__(256) wt_setup(const float* __restrict__ W1,
                                                const float* __restrict__ W2,
                                                short* __restrict__ W1t,
                                                short* __restrict__ W2t) {
  int idx = blockIdx.x * 256 + threadIdx.x;      // 384 blocks -> 98304 threads
  if (idx < 32768) {                             // W1t [256][128]
    int f = idx >> 7, k = idx & 127;
    float v = (k < DIN_) ? W1[k * H_ + f] : 0.f;
    W1t[idx] = f2bf(v);
  } else {                                       // W2t [256][256]
    int j = idx - 32768;
    int f = j >> 8, k = j & 255;
    W2t[j] = f2bf(W2[k * H_ + f]);
  }
}

__global__ void __launch_bounds__(512, 2) gnn_fused(
    const float* __restrict__ mM, const float* __restrict__ nf,
    const float* __restrict__ b1, const float* __restrict__ b2,
    const float* __restrict__ Wc, const float* __restrict__ bc,
    const short* __restrict__ W1t, const short* __restrict__ W2t,
    float* __restrict__ out)
{
  extern __shared__ char smem[];
  const int b    = blockIdx.x;
  const int tid  = threadIdx.x;
  const int lane = tid & 63;
  const int w    = tid >> 6;
  const int wm   = w >> 2;      // 0..1 : m/c tile group (4 tiles each)
  const int wn   = w & 3;       // 0..3 : 16-col group within 64-wide f tile
  const int ln16 = lane & 15;
  const int lq   = lane >> 4;

  float* dinvp = (float*)(smem + DINV_OFF);

  // ---- Phase 0a: zero At ----
  for (int i = tid; i < (RP * AT_P * 2) / 16; i += 512)
    *(int4v*)(smem + AT_OFF + i * 16) = (int4v){0, 0, 0, 0};
  __syncthreads();

  // ---- Phase 0b: fill At (transposed, +1 on diag) ----
  {
    const float* mB = mM + (size_t)b * (R_ * R_);
    for (int i = tid; i < R_ * R_; i += 512) {
      int r = i / R_, c = i - r * R_;
      float v = mB[i];
      v = v > 0.f ? v : 0.f;
      if (r == c) v += 1.f;
      *(short*)(smem + AT_OFF + (c * AT_P + r) * 2) = f2bf(v);
    }
  }
  __syncthreads();

  // ---- Phase 0c: deg / dinv  (deg[c] = sum_r At[c][r] == A.sum(axis=1)+1) ----
  if (tid < RP) {
    float dv = 0.f;
    if (tid < R_) {
      float s = 0.f;
      const short* row = (const short*)(smem + AT_OFF + tid * AT_P * 2);
      for (int r = 0; r < R_; ++r) s += bf2f(row[r]);
      dv = rsqrtf(s);
    }
    dinvp[tid] = dv;   // pad rows get 0 -> kills padded xs rows
  }
  __syncthreads();

  // ---- At fragments, register-resident for both layers ----
  short8 atf[4][4];
#pragma unroll
  for (int ct = 0; ct < 4; ++ct) {
    int c = (wm * 4 + ct) * 16 + ln16;
#pragma unroll
    for (int ks = 0; ks < 4; ++ks)
      atf[ct][ks] = *(const short8*)(smem + AT_OFF + (c * AT_P + ks * 32 + lq * 8) * 2);
  }

  // ---- Layer-1 A fragments (node features), masked loads, register-resident ----
  short8 a1f[4][4];
#pragma unroll
  for (int mt = 0; mt < 4; ++mt) {
    int r = (wm * 4 + mt) * 16 + ln16;
    int rc = r < R_ ? r : (R_ - 1);
    const float* src = nf + (size_t)(b * R_ + rc) * DIN_;
#pragma unroll
    for (int ks = 0; ks < 4; ++ks) {
      int k0 = ks * 32 + lq * 8;
      short8 v;
#pragma unroll
      for (int e = 0; e < 8; ++e) {
        int k = k0 + e;
        int kc = k < DIN_ ? k : (DIN_ - 1);
        float t = src[kc];
        t = (r < R_ && k < DIN_) ? t : 0.f;
        v[e] = f2bf(t);
      }
      a1f[mt][ks] = v;
    }
  }

  float ps0 = 0.f, ps1 = 0.f;

  // ================= Layer 1 =================
#pragma unroll 1
  for (int ft = 0; ft < 4; ++ft) {
    { // stage W1t slice [64][128] -> Wbuf [64][136]
      const int4v* src = (const int4v*)(W1t + (size_t)ft * 64 * 128);
      for (int ch = tid; ch < 64 * 16; ch += 512) {
        int row = ch >> 4, cc = ch & 15;
        *(int4v*)(smem + WB_OFF + row * 272 + cc * 16) = src[ch];
      }
    }
    __syncthreads();

    // xw = X @ W1 (M=node rows, K=116->128)
    f32x4 acc[4];
#pragma unroll
    for (int mt = 0; mt < 4; ++mt) acc[mt] = (f32x4){0.f, 0.f, 0.f, 0.f};
#pragma unroll
    for (int ks = 0; ks < 4; ++ks) {
      short8 bf = *(const short8*)(smem + WB_OFF + (wn * 16 + ln16) * 272 + (ks * 32 + lq * 8) * 2);
#pragma unroll
      for (int mt = 0; mt < 4; ++mt)
        acc[mt] = __builtin_amdgcn_mfma_f32_16x16x32_bf16(a1f[mt][ks], bf, acc[mt], 0, 0, 0);
    }
    // xs = dinv * xw -> xsT[f][r]
#pragma unroll
    for (int mt = 0; mt < 4; ++mt) {
      int r0 = (wm * 4 + mt) * 16 + lq * 4;
      short4v xv;
#pragma unroll
      for (int e = 0; e < 4; ++e) xv[e] = f2bf(acc[mt][e] * dinvp[r0 + e]);
      *(short4v*)(smem + XST_OFF + ((wn * 16 + ln16) * XST_P + r0) * 2) = xv;
    }
    __syncthreads();

    // agg = At' @ xs  (self-loop folded into diag)
    f32x4 acc2[4];
#pragma unroll
    for (int ct = 0; ct < 4; ++ct) acc2[ct] = (f32x4){0.f, 0.f, 0.f, 0.f};
#pragma unroll
    for (int ks = 0; ks < 4; ++ks) {
      short8 bx = *(const short8*)(smem + XST_OFF + ((wn * 16 + ln16) * XST_P + ks * 32 + lq * 8) * 2);
#pragma unroll
      for (int ct = 0; ct < 4; ++ct)
        acc2[ct] = __builtin_amdgcn_mfma_f32_16x16x32_bf16(atf[ct][ks], bx, acc2[ct], 0, 0, 0);
    }
    int fglob = ft * 64 + wn * 16 + ln16;
    float bias = b1[fglob];
#pragma unroll
    for (int ct = 0; ct < 4; ++ct) {
      int c0 = (wm * 4 + ct) * 16 + lq * 4;
#pragma unroll
      for (int e = 0; e < 4; ++e) {
        int c = c0 + e;
        float h = dinvp[c] * acc2[ct][e] + bias;
        h = h > 0.f ? h : 0.2f * h;
        *(short*)(smem + H1_OFF + (c * H1_P + fglob) * 2) = f2bf(h);
      }
    }
    __syncthreads();
  }

  // ================= Layer 2 =================
#pragma unroll 1
  for (int ft = 0; ft < 4; ++ft) {
    { // stage W2t slice [64][256] -> Wbuf [64][264]
      const int4v* src = (const int4v*)(W2t + (size_t)ft * 64 * 256);
      for (int ch = tid; ch < 64 * 32; ch += 512) {
        int row = ch >> 5, cc = ch & 31;
        *(int4v*)(smem + WB_OFF + row * 528 + cc * 16) = src[ch];
      }
    }
    __syncthreads();

    // xw2 = H1 @ W2 (K=256)
    f32x4 acc[4];
#pragma unroll
    for (int mt = 0; mt < 4; ++mt) acc[mt] = (f32x4){0.f, 0.f, 0.f, 0.f};
#pragma unroll
    for (int ks = 0; ks < 8; ++ks) {
      short8 bf = *(const short8*)(smem + WB_OFF + (wn * 16 + ln16) * 528 + (ks * 32 + lq * 8) * 2);
#pragma unroll
      for (int mt = 0; mt < 4; ++mt) {
        int rr = (wm * 4 + mt) * 16 + ln16;
        short8 af = *(const short8*)(smem + H1_OFF + (rr * H1_P + ks * 32 + lq * 8) * 2);
        acc[mt] = __builtin_amdgcn_mfma_f32_16x16x32_bf16(af, bf, acc[mt], 0, 0, 0);
      }
    }
#pragma unroll
    for (int mt = 0; mt < 4; ++mt) {
      int r0 = (wm * 4 + mt) * 16 + lq * 4;
      short4v xv;
#pragma unroll
      for (int e = 0; e < 4; ++e) xv[e] = f2bf(acc[mt][e] * dinvp[r0 + e]);
      *(short4v*)(smem + XST_OFF + ((wn * 16 + ln16) * XST_P + r0) * 2) = xv;
    }
    __syncthreads();

    f32x4 acc2[4];
#pragma unroll
    for (int ct = 0; ct < 4; ++ct) acc2[ct] = (f32x4){0.f, 0.f, 0.f, 0.f};
#pragma unroll
    for (int ks = 0; ks < 4; ++ks) {
      short8 bx = *(const short8*)(smem + XST_OFF + ((wn * 16 + ln16) * XST_P + ks * 32 + lq * 8) * 2);
#pragma unroll
      for (int ct = 0; ct < 4; ++ct)
        acc2[ct] = __builtin_amdgcn_mfma_f32_16x16x32_bf16(atf[ct][ks], bx, acc2[ct], 0, 0, 0);
    }
    int fglob = ft * 64 + wn * 16 + ln16;
    float bias = b2[fglob];
#pragma unroll
    for (int ct = 0; ct < 4; ++ct) {
      int c0 = (wm * 4 + ct) * 16 + lq * 4;
#pragma unroll
      for (int e = 0; e < 4; ++e) {
        int c = c0 + e;
        if (c < R_) {
          float h = dinvp[c] * acc2[ct][e] + bias;
          h = h > 0.f ? h : 0.2f * h;
          size_t j = (size_t)c * H_ + fglob;
          ps0 += h * Wc[j];
          ps1 += h * Wc[(size_t)(H_ * R_) + j];
        }
      }
    }
    __syncthreads();
  }

  // ---- classifier reduction ----
#pragma unroll
  for (int off = 32; off; off >>= 1) {
    ps0 += __shfl_xor(ps0, off, 64);
    ps1 += __shfl_xor(ps1, off, 64);
  }
  float* red = (float*)(smem + RED_OFF);
  if (lane == 0) { red[w * 2] = ps0; red[w * 2 + 1] = ps1; }
  __syncthreads();
  if (tid == 0) {
    float s0 = 0.f, s1 = 0.f;
    for (int i = 0; i < 8; ++i) { s0 += red[i * 2]; s1 += red[i * 2 + 1]; }
    out[b * 2 + 0] = s0 + bc[0];
    out[b * 2 + 1] = s1 + bc[1];
  }
}

extern "C" void kernel_launch(void* const* d_in, const int* in_sizes, int n_in,
                              void* d_out, int out_size, void* d_ws, size_t ws_size,
                              hipStream_t stream) {
  const float* mM = (const float*)d_in[0];
  const float* nf = (const float*)d_in[1];
  const float* W1 = (const float*)d_in[2];
  const float* b1 = (const float*)d_in[3];
  const float* W2 = (const float*)d_in[4];
  const float* b2 = (const float*)d_in[5];
  const float* Wc = (const float*)d_in[6];
  const float* bc = (const float*)d_in[7];
  float* out = (float*)d_out;

  short* W1t = (short*)d_ws;            // 32768 bf16
  short* W2t = W1t + 32768;             // 65536 bf16

  wt_setup<<<384, 256, 0, stream>>>(W1, W2, W1t, W2t);

  hipFuncSetAttribute((const void*)gnn_fused,
                      hipFuncAttributeMaxDynamicSharedMemorySize, LDS_SIZE);
  gnn_fused<<<512, 512, LDS_SIZE, stream>>>(mM, nf, b1, b2, Wc, bc, W1t, W2t, out);
}